// Round 10
// baseline (682.875 us; speedup 1.0000x reference)
//
#include <hip/hip_runtime.h>
#include <hip/hip_bf16.h>

// Problem constants
#define EMBD   1024
#define NHEAD  16
#define HDIM   64
#define SEQ    2048
#define BATCH  2
#define MROWS  4096          // BATCH*SEQ
#define NQKV   3072          // 3*EMBD

using floatx4 = __attribute__((ext_vector_type(4))) float;
using short8  = __attribute__((ext_vector_type(8))) short;

static __device__ __forceinline__ float bf2f(unsigned short u) {
    unsigned int v = ((unsigned int)u) << 16;
    return __uint_as_float(v);
}
static __device__ __forceinline__ unsigned short f2bf(float f) {
    __hip_bfloat16 h = __float2bfloat16(f);   // RNE
    return *reinterpret_cast<unsigned short*>(&h);
}

// async 16B global->LDS (m97 pattern; LDS dest is wave-uniform base + lane*16)
static __device__ __forceinline__ void stage16(const unsigned short* g, unsigned short* l) {
    __builtin_amdgcn_global_load_lds(
        (const __attribute__((address_space(1))) unsigned int*)g,
        (__attribute__((address_space(3))) unsigned int*)l, 16, 0, 0);
}

// ---------------------------------------------------------------------------
// Cast kernels: fp32 -> split bf16 (hi + lo), w transposed to [N][K].
// ---------------------------------------------------------------------------
__global__ __launch_bounds__(256) void cast_x(
    const float* __restrict__ x, unsigned short* __restrict__ xh,
    unsigned short* __restrict__ xl)
{
    int idx = (blockIdx.x * 256 + threadIdx.x) * 4;
    float4 v = *(const float4*)(x + idx);
    ushort4 h, l;
    h.x = f2bf(v.x); l.x = f2bf(v.x - bf2f(h.x));
    h.y = f2bf(v.y); l.y = f2bf(v.y - bf2f(h.y));
    h.z = f2bf(v.z); l.z = f2bf(v.z - bf2f(h.z));
    h.w = f2bf(v.w); l.w = f2bf(v.w - bf2f(h.w));
    *(ushort4*)(xh + idx) = h;
    *(ushort4*)(xl + idx) = l;
}

// w [1024][N] fp32 -> wT_h/wT_l [N][1024] bf16 (64x64 LDS-tiled transpose)
__global__ __launch_bounds__(256) void cast_wT(
    const float* __restrict__ w, unsigned short* __restrict__ wT_h,
    unsigned short* __restrict__ wT_l, int N, int withLo)
{
    __shared__ unsigned short th[64][65];
    __shared__ unsigned short tl[64][65];
    const int k0 = blockIdx.y * 64, n0 = blockIdx.x * 64;
    const int t = threadIdx.x;
    const int r = t >> 4, c = (t & 15) * 4;
    for (int rr = r; rr < 64; rr += 16) {
        float4 v = *(const float4*)(w + (size_t)(k0 + rr) * N + n0 + c);
        unsigned short h0 = f2bf(v.x), h1 = f2bf(v.y), h2 = f2bf(v.z), h3 = f2bf(v.w);
        th[rr][c + 0] = h0; tl[rr][c + 0] = f2bf(v.x - bf2f(h0));
        th[rr][c + 1] = h1; tl[rr][c + 1] = f2bf(v.y - bf2f(h1));
        th[rr][c + 2] = h2; tl[rr][c + 2] = f2bf(v.z - bf2f(h2));
        th[rr][c + 3] = h3; tl[rr][c + 3] = f2bf(v.w - bf2f(h3));
    }
    __syncthreads();
    for (int rr = r; rr < 64; rr += 16) {
        ushort4 h;
        h.x = th[c + 0][rr]; h.y = th[c + 1][rr];
        h.z = th[c + 2][rr]; h.w = th[c + 3][rr];
        *(ushort4*)(wT_h + (size_t)(n0 + rr) * 1024 + k0 + c) = h;
        if (withLo) {
            ushort4 l;
            l.x = tl[c + 0][rr]; l.y = tl[c + 1][rr];
            l.z = tl[c + 2][rr]; l.w = tl[c + 3][rr];
            *(ushort4*)(wT_l + (size_t)(n0 + rr) * 1024 + k0 + c) = l;
        }
    }
}

// ---------------------------------------------------------------------------
// qkv = x @ w_qkv via split-bf16 MFMA (hh + hl + lh), fused RoPE.
// 128x128 tile, BK=32, 4 waves (each 64x64).  Spill-free K-loop: the three
// split passes run sequentially with at most 8 operand fragments (32 VGPRs)
// live: [ah·bh] -> [ah·bl] -> [al·bh(reload)].  launch_bounds(256,1) lifts
// any occupancy-driven register cap (R9: spills -> 1.5 GB scratch writes).
// ---------------------------------------------------------------------------
__global__ __launch_bounds__(256, 1) void gemm_qkv_mfma(
    const unsigned short* __restrict__ xh, const unsigned short* __restrict__ xl,
    const unsigned short* __restrict__ whT, const unsigned short* __restrict__ wlT,
    unsigned short* __restrict__ qst, unsigned short* __restrict__ kst,
    unsigned short* __restrict__ vtT)
{
    __shared__ unsigned short smem[16384];   // 32 KB: 4 tiles [128][32]
    unsigned short* sXH = smem;
    unsigned short* sXL = smem + 4096;
    unsigned short* sWH = smem + 8192;
    unsigned short* sWL = smem + 12288;

    const int t = threadIdx.x, wave = t >> 6, lane = t & 63;
    const int col = lane & 15, quad = lane >> 4;
    const int n0 = blockIdx.x * 128;
    const int m0 = blockIdx.y * 128;
    const int which = n0 >> 10;              // block-uniform: 0=q,1=k,2=v
    const int wm = (wave >> 1) * 64, wn = (wave & 1) * 64;

    const int srow = lane >> 2;              // staging row within 16-row slab
    const int scol = (lane & 3) * 8;         // staging k-offset (elems)

    floatx4 acc[4][4];
    #pragma unroll
    for (int i = 0; i < 4; ++i)
        #pragma unroll
        for (int j = 0; j < 4; ++j) acc[i][j] = (floatx4){0.f, 0.f, 0.f, 0.f};

    const unsigned short* gx_h = xh + (size_t)m0 * 1024;
    const unsigned short* gx_l = xl + (size_t)m0 * 1024;
    const unsigned short* gw_h = whT + (size_t)n0 * 1024;
    const unsigned short* gw_l = wlT + (size_t)n0 * 1024;

    // fragment LDS offsets (elements)
    const int aoff = (wm + col) * 32 + quad * 8;
    const int boff = (wn + col) * 32 + quad * 8;

    for (int k0 = 0; k0 < 1024; k0 += 32) {
        __syncthreads();
        #pragma unroll
        for (int hh = 0; hh < 2; ++hh) {
            const int rbase = hh * 64 + wave * 16;        // wave-uniform
            const size_t go = (size_t)(rbase + srow) * 1024 + k0 + scol;
            const int lo = rbase * 32;                    // wave-uniform LDS offset
            stage16(gx_h + go, sXH + lo);
            stage16(gx_l + go, sXL + lo);
            stage16(gw_h + go, sWH + lo);
            stage16(gw_l + go, sWL + lo);
        }
        __syncthreads();

        short8 af[4], bf[4];

        // helper: one 16-MFMA sweep (orientation by 'which', block-uniform)
        auto sweep = [&]() {
            if (which < 2) {
                #pragma unroll
                for (int fm = 0; fm < 4; ++fm)
                    #pragma unroll
                    for (int fn = 0; fn < 4; ++fn)
                        acc[fm][fn] = __builtin_amdgcn_mfma_f32_16x16x32_bf16(
                            bf[fn], af[fm], acc[fm][fn], 0, 0, 0);   // C^T
            } else {
                #pragma unroll
                for (int fm = 0; fm < 4; ++fm)
                    #pragma unroll
                    for (int fn = 0; fn < 4; ++fn)
                        acc[fm][fn] = __builtin_amdgcn_mfma_f32_16x16x32_bf16(
                            af[fm], bf[fn], acc[fm][fn], 0, 0, 0);
            }
        };

        // pass 1: ah . bh
        #pragma unroll
        for (int f = 0; f < 4; ++f) {
            af[f] = *(const short8*)&sXH[aoff + f * 16 * 32];
            bf[f] = *(const short8*)&sWH[boff + f * 16 * 32];
        }
        sweep();
        // pass 2: ah . bl   (af unchanged)
        #pragma unroll
        for (int f = 0; f < 4; ++f)
            bf[f] = *(const short8*)&sWL[boff + f * 16 * 32];
        sweep();
        // pass 3: al . bh   (reload bh)
        #pragma unroll
        for (int f = 0; f < 4; ++f) {
            af[f] = *(const short8*)&sXL[aoff + f * 16 * 32];
            bf[f] = *(const short8*)&sWH[boff + f * 16 * 32];
        }
        sweep();
    }

    const float RLOG = 9.210340371976184f / 32.0f;   // ln(10000)/32
    if (which < 2) {
        unsigned short* dst = (which == 0) ? qst : kst;
        const float scale = (which == 0) ? 0.125f : 1.0f;   // D^-0.5 folded into q
        #pragma unroll
        for (int fm = 0; fm < 4; ++fm) {
            const int s_g = m0 + wm + fm * 16 + col;     // C^T col = x row = s
            const int b = s_g >> 11, s = s_g & 2047;
            const float sf = (float)s;
            #pragma unroll
            for (int fn = 0; fn < 4; ++fn) {
                const int nl = (n0 & 1023) + wn + fn * 16 + quad * 4;  // C^T row = w col
                const int h = nl >> 6;
                const int d0 = nl & 63;                  // multiple of 4
                floatx4 c = acc[fm][fn];
                float o_[4];
                #pragma unroll
                for (int pp = 0; pp < 2; ++pp) {
                    int de = d0 + pp * 2;                // even
                    float fe = __expf(-(float)(de & 31) * RLOG);
                    float fo = __expf(-(float)((de + 1) & 31) * RLOG);
                    float se, ce, so, co;
                    sincosf(sf * fe, &se, &ce);
                    sincosf(sf * fo, &so, &co);
                    float qe = c[pp * 2], qo = c[pp * 2 + 1];
                    o_[pp * 2]     = (qe * ce - qo * se) * scale;
                    o_[pp * 2 + 1] = (qo * co + qe * so) * scale;
                }
                ushort4 o4;
                o4.x = f2bf(o_[0]); o4.y = f2bf(o_[1]);
                o4.z = f2bf(o_[2]); o4.w = f2bf(o_[3]);
                *(ushort4*)(dst + ((size_t)(b * 16 + h) * 2048 + s) * 64 + d0) = o4;
            }
        }
    } else {
        #pragma unroll
        for (int fm = 0; fm < 4; ++fm) {
            const int m = m0 + wm + fm * 16 + quad * 4;  // 4 consecutive s (regs)
            const int b = m >> 11, s0 = m & 2047;
            #pragma unroll
            for (int fn = 0; fn < 4; ++fn) {
                const int nl = (n0 & 1023) + wn + fn * 16 + col;
                const int h = nl >> 6;
                const int d = nl & 63;
                floatx4 c = acc[fm][fn];
                ushort4 o4;
                o4.x = f2bf(c[0]); o4.y = f2bf(c[1]);
                o4.z = f2bf(c[2]); o4.w = f2bf(c[3]);
                *(ushort4*)(vtT + ((size_t)(b * 16 + h) * 64 + d) * 2048 + s0) = o4;
            }
        }
    }
}

// ---------------------------------------------------------------------------
// Attention: complement-masked, bf16 MFMA, single pass (R8-verified).
// ---------------------------------------------------------------------------
__global__ __launch_bounds__(256) void attn_mfma(
    const unsigned short* __restrict__ qst,
    const unsigned short* __restrict__ kst,
    const unsigned short* __restrict__ vtT,
    unsigned short* __restrict__ attn)
{
    __shared__ unsigned short p_tile[4][16][32];

    const int tid  = threadIdx.x;
    const int wave = tid >> 6;
    const int lane = tid & 63;
    const int col  = lane & 15;
    const int quad = lane >> 4;

    const int bh   = blockIdx.x >> 5;
    const int row0 = (blockIdx.x & 31) * 64 + wave * 16;

    const size_t base = (size_t)bh * SEQ * HDIM;

    const unsigned short* qp = qst + base + (size_t)(row0 + col) * HDIM + quad * 8;
    short8 aq0 = *(const short8*)(qp);
    short8 aq1 = *(const short8*)(qp + 32);

    int iR[4], ngR[4], j0R[4];
    #pragma unroll
    for (int r = 0; r < 4; ++r) {
        int i = row0 + quad * 4 + r;
        iR[r] = i;
        ngR[r] = (i + 1 < 4) ? (i + 1) : 4;
        int L = i - 128;
        int bs = (i >> 8) << 8;
        if (bs < L) L = bs;
        if (L < 0) L = 0;
        j0R[r] = (L > 4) ? L : 4;
    }

    floatx4 o0 = {0.f, 0.f, 0.f, 0.f}, o1 = o0, o2 = o0, o3 = o0;
    float lsum[4] = {0.f, 0.f, 0.f, 0.f};

    for (int c32 = 0; c32 < SEQ / 32; ++c32) {
        const int kc0 = c32 * 32;
        #pragma unroll
        for (int h16 = 0; h16 < 2; ++h16) {
            const int kc = kc0 + h16 * 16;
            const unsigned short* kp = kst + base + (size_t)(kc + col) * HDIM + quad * 8;
            short8 bk0 = *(const short8*)(kp);
            short8 bk1 = *(const short8*)(kp + 32);
            floatx4 s = {0.f, 0.f, 0.f, 0.f};
            s = __builtin_amdgcn_mfma_f32_16x16x32_bf16(aq0, bk0, s, 0, 0, 0);
            s = __builtin_amdgcn_mfma_f32_16x16x32_bf16(aq1, bk1, s, 0, 0, 0);
            const int j = kc + col;
            #pragma unroll
            for (int r = 0; r < 4; ++r) {
                bool excl = (j < ngR[r]) || (j >= j0R[r] && j <= iR[r]);
                float p = excl ? 0.f : __expf(s[r]);
                unsigned short pb = f2bf(p);
                lsum[r] += bf2f(pb);
                p_tile[wave][quad * 4 + r][h16 * 16 + col] = pb;
            }
        }
        __syncthreads();
        short8 ap = *(const short8*)&p_tile[wave][col][quad * 8];
        const unsigned short* vp = vtT + base + (size_t)col * SEQ + kc0 + quad * 8;
        short8 bv0 = *(const short8*)(vp);
        short8 bv1 = *(const short8*)(vp + 16 * SEQ);
        short8 bv2 = *(const short8*)(vp + 32 * SEQ);
        short8 bv3 = *(const short8*)(vp + 48 * SEQ);
        o0 = __builtin_amdgcn_mfma_f32_16x16x32_bf16(ap, bv0, o0, 0, 0, 0);
        o1 = __builtin_amdgcn_mfma_f32_16x16x32_bf16(ap, bv1, o1, 0, 0, 0);
        o2 = __builtin_amdgcn_mfma_f32_16x16x32_bf16(ap, bv2, o2, 0, 0, 0);
        o3 = __builtin_amdgcn_mfma_f32_16x16x32_bf16(ap, bv3, o3, 0, 0, 0);
    }

    #pragma unroll
    for (int r = 0; r < 4; ++r) {
        float v = lsum[r];
        v += __shfl_xor(v, 1);
        v += __shfl_xor(v, 2);
        v += __shfl_xor(v, 4);
        v += __shfl_xor(v, 8);
        lsum[r] = v;
    }

    const int b = bh >> 4, h = bh & 15;
    #pragma unroll
    for (int r = 0; r < 4; ++r) {
        float inv = 1.0f / lsum[r];
        unsigned short* orow = attn + ((size_t)(b * SEQ + iR[r])) * EMBD + h * HDIM + col;
        orow[0]  = f2bf(o0[r] * inv);
        orow[16] = f2bf(o1[r] * inv);
        orow[32] = f2bf(o2[r] * inv);
        orow[48] = f2bf(o3[r] * inv);
    }
}

// ---------------------------------------------------------------------------
// Output projection: out = attn(bf16) @ w_out via 1-pass bf16 MFMA -> fp32.
// B fragments loaded one-at-a-time to bound register pressure.
// ---------------------------------------------------------------------------
__global__ __launch_bounds__(256, 1) void gemm_out_mfma(
    const unsigned short* __restrict__ A,      // [4096][1024] bf16
    const unsigned short* __restrict__ woT,    // [1024 n][1024 k] bf16
    float* __restrict__ out)
{
    __shared__ unsigned short smem[8192];      // 16 KB: 2 tiles [128][32]
    unsigned short* sA = smem;
    unsigned short* sB = smem + 4096;

    const int t = threadIdx.x, wave = t >> 6, lane = t & 63;
    const int col = lane & 15, quad = lane >> 4;
    const int n0 = blockIdx.x * 128;
    const int m0 = blockIdx.y * 128;
    const int wm = (wave >> 1) * 64, wn = (wave & 1) * 64;
    const int srow = lane >> 2;
    const int scol = (lane & 3) * 8;

    floatx4 acc[4][4];
    #pragma unroll
    for (int i = 0; i < 4; ++i)
        #pragma unroll
        for (int j = 0; j < 4; ++j) acc[i][j] = (floatx4){0.f, 0.f, 0.f, 0.f};

    const unsigned short* gA = A   + (size_t)m0 * 1024;
    const unsigned short* gB = woT + (size_t)n0 * 1024;

    const int aoff = (wm + col) * 32 + quad * 8;
    const int boff = (wn + col) * 32 + quad * 8;

    for (int k0 = 0; k0 < 1024; k0 += 32) {
        __syncthreads();
        #pragma unroll
        for (int hh = 0; hh < 2; ++hh) {
            const int rbase = hh * 64 + wave * 16;
            const size_t go = (size_t)(rbase + srow) * 1024 + k0 + scol;
            const int lo = rbase * 32;
            stage16(gA + go, sA + lo);
            stage16(gB + go, sB + lo);
        }
        __syncthreads();

        short8 af[4];
        #pragma unroll
        for (int f = 0; f < 4; ++f)
            af[f] = *(const short8*)&sA[aoff + f * 16 * 32];
        #pragma unroll
        for (int fn = 0; fn < 4; ++fn) {
            short8 bf1 = *(const short8*)&sB[boff + fn * 16 * 32];
            #pragma unroll
            for (int fm = 0; fm < 4; ++fm)
                acc[fm][fn] = __builtin_amdgcn_mfma_f32_16x16x32_bf16(
                    af[fm], bf1, acc[fm][fn], 0, 0, 0);
        }
    }

    #pragma unroll
    for (int fm = 0; fm < 4; ++fm) {
        const int m = m0 + wm + fm * 16 + quad * 4;
        #pragma unroll
        for (int fn = 0; fn < 4; ++fn) {
            const int n = n0 + wn + fn * 16 + col;
            floatx4 c = acc[fm][fn];
            out[(size_t)(m + 0) * 1024 + n] = c[0];
            out[(size_t)(m + 1) * 1024 + n] = c[1];
            out[(size_t)(m + 2) * 1024 + n] = c[2];
            out[(size_t)(m + 3) * 1024 + n] = c[3];
        }
    }
}

// ---------------------------------------------------------------------------
extern "C" void kernel_launch(void* const* d_in, const int* in_sizes, int n_in,
                              void* d_out, int out_size, void* d_ws, size_t ws_size,
                              hipStream_t stream) {
    const float* x     = (const float*)d_in[0];  // (2,2048,1024)
    const float* w_qkv = (const float*)d_in[1];  // (1024,3072)
    const float* w_out = (const float*)d_in[2];  // (1024,1024)
    float* out = (float*)d_out;                  // (2,2048,1024)

    // Workspace map (bf16 elems; ~62 MB of the proven >=64 MB):
    unsigned short* ws16 = (unsigned short*)d_ws;
    unsigned short* xh  = ws16;              // 4,194,304
    unsigned short* xl  = ws16 +  4194304;   // 4,194,304
    unsigned short* whT = ws16 +  8388608;   // 3,145,728  [3072][1024]
    unsigned short* wlT = ws16 + 11534336;   // 3,145,728
    unsigned short* woT = ws16 + 14680064;   // 1,048,576  [1024][1024]
    unsigned short* qst = ws16 + 15728640;   // 4,194,304  [bh][s][d]
    unsigned short* kst = ws16 + 19922944;   // 4,194,304  [bh][s][d]
    unsigned short* vtT = ws16 + 24117248;   // 4,194,304  [bh][d][s]
    unsigned short* aws = ws16 + 28311552;   // 4,194,304  [M][E] bf16

    dim3 blk(256);
    cast_x<<<dim3(4096), blk, 0, stream>>>(x, xh, xl);
    cast_wT<<<dim3(48, 16), blk, 0, stream>>>(w_qkv, whT, wlT, NQKV, 1);
    cast_wT<<<dim3(16, 16), blk, 0, stream>>>(w_out, woT, woT, EMBD, 0);

    gemm_qkv_mfma<<<dim3(NQKV / 128, MROWS / 128), blk, 0, stream>>>(
        xh, xl, whT, wlT, qst, kst, vtT);

    attn_mfma<<<dim3(32 * 32), blk, 0, stream>>>(qst, kst, vtT, aws);

    gemm_out_mfma<<<dim3(EMBD / 128, MROWS / 128), blk, 0, stream>>>(aws, woT, out);
}

// Round 11
// 589.340 us; speedup vs baseline: 1.1587x; 1.1587x over previous
//
#include <hip/hip_runtime.h>
#include <hip/hip_bf16.h>

// Problem constants
#define EMBD   1024
#define NHEAD  16
#define HDIM   64
#define SEQ    2048
#define BATCH  2
#define MROWS  4096          // BATCH*SEQ
#define NQKV   3072          // 3*EMBD

using floatx4 = __attribute__((ext_vector_type(4))) float;
using short8  = __attribute__((ext_vector_type(8))) short;

static __device__ __forceinline__ float bf2f(unsigned short u) {
    unsigned int v = ((unsigned int)u) << 16;
    return __uint_as_float(v);
}
static __device__ __forceinline__ unsigned short f2bf(float f) {
    __hip_bfloat16 h = __float2bfloat16(f);   // RNE
    return *reinterpret_cast<unsigned short*>(&h);
}

// async 16B global->LDS (m97 pattern; LDS dest is wave-uniform base + lane*16)
static __device__ __forceinline__ void stage16(const unsigned short* g, unsigned short* l) {
    __builtin_amdgcn_global_load_lds(
        (const __attribute__((address_space(1))) unsigned int*)g,
        (__attribute__((address_space(3))) unsigned int*)l, 16, 0, 0);
}

// ---------------------------------------------------------------------------
// Cast kernels: x -> split bf16 (hi + lo); w -> bf16, transposed to [N][K].
// ---------------------------------------------------------------------------
__global__ __launch_bounds__(256) void cast_x(
    const float* __restrict__ x, unsigned short* __restrict__ xh,
    unsigned short* __restrict__ xl)
{
    int idx = (blockIdx.x * 256 + threadIdx.x) * 4;
    float4 v = *(const float4*)(x + idx);
    ushort4 h, l;
    h.x = f2bf(v.x); l.x = f2bf(v.x - bf2f(h.x));
    h.y = f2bf(v.y); l.y = f2bf(v.y - bf2f(h.y));
    h.z = f2bf(v.z); l.z = f2bf(v.z - bf2f(h.z));
    h.w = f2bf(v.w); l.w = f2bf(v.w - bf2f(h.w));
    *(ushort4*)(xh + idx) = h;
    *(ushort4*)(xl + idx) = l;
}

// w [1024][N] fp32 -> wT [N][1024] bf16 (64x64 LDS-tiled transpose)
__global__ __launch_bounds__(256) void cast_wT(
    const float* __restrict__ w, unsigned short* __restrict__ wT, int N)
{
    __shared__ unsigned short th[64][65];
    const int k0 = blockIdx.y * 64, n0 = blockIdx.x * 64;
    const int t = threadIdx.x;
    const int r = t >> 4, c = (t & 15) * 4;
    for (int rr = r; rr < 64; rr += 16) {
        float4 v = *(const float4*)(w + (size_t)(k0 + rr) * N + n0 + c);
        th[rr][c + 0] = f2bf(v.x);
        th[rr][c + 1] = f2bf(v.y);
        th[rr][c + 2] = f2bf(v.z);
        th[rr][c + 3] = f2bf(v.w);
    }
    __syncthreads();
    for (int rr = r; rr < 64; rr += 16) {
        ushort4 h;
        h.x = th[c + 0][rr]; h.y = th[c + 1][rr];
        h.z = th[c + 2][rr]; h.w = th[c + 3][rr];
        *(ushort4*)(wT + (size_t)(n0 + rr) * 1024 + k0 + c) = h;
    }
}

// ---------------------------------------------------------------------------
// qkv = x @ w_qkv via split-x bf16 MFMA (xh.wb + xl.wb), fused RoPE.
// 128x128 tile, BK=32, 4 waves (each 64x64). 24 KB LDS (3 tiles [128][32]).
// q/k: operand-swapped MFMA (acc = C^T) -> lane regs = 4 consecutive d at
// fixed s -> in-lane RoPE pairs, 8B stores into [bh][s][d].
// v: normal orientation -> 4 consecutive s at fixed d -> 8B stores into
// transposed [bh][d][s].
// ---------------------------------------------------------------------------
__global__ __launch_bounds__(256) void gemm_qkv_mfma(
    const unsigned short* __restrict__ xh, const unsigned short* __restrict__ xl,
    const unsigned short* __restrict__ wbT,
    unsigned short* __restrict__ qst, unsigned short* __restrict__ kst,
    unsigned short* __restrict__ vtT)
{
    __shared__ unsigned short smem[12288];   // 24 KB: 3 tiles [128][32]
    unsigned short* sXH = smem;
    unsigned short* sXL = smem + 4096;
    unsigned short* sWB = smem + 8192;

    const int t = threadIdx.x, wave = t >> 6, lane = t & 63;
    const int col = lane & 15, quad = lane >> 4;
    const int n0 = blockIdx.x * 128;
    const int m0 = blockIdx.y * 128;
    const int which = n0 >> 10;              // block-uniform: 0=q,1=k,2=v
    const int wm = (wave >> 1) * 64, wn = (wave & 1) * 64;

    const int srow = lane >> 2;              // staging row within 16-row slab
    const int scol = (lane & 3) * 8;         // staging k-offset (elems)

    floatx4 acc[4][4];
    #pragma unroll
    for (int i = 0; i < 4; ++i)
        #pragma unroll
        for (int j = 0; j < 4; ++j) acc[i][j] = (floatx4){0.f, 0.f, 0.f, 0.f};

    const unsigned short* gx_h = xh  + (size_t)m0 * 1024;
    const unsigned short* gx_l = xl  + (size_t)m0 * 1024;
    const unsigned short* gw   = wbT + (size_t)n0 * 1024;

    const int aoff = (wm + col) * 32 + quad * 8;   // LDS elem offsets
    const int boff = (wn + col) * 32 + quad * 8;

    for (int k0 = 0; k0 < 1024; k0 += 32) {
        __syncthreads();
        #pragma unroll
        for (int hh = 0; hh < 2; ++hh) {
            const int rbase = hh * 64 + wave * 16;        // wave-uniform
            const size_t go = (size_t)(rbase + srow) * 1024 + k0 + scol;
            const int lo = rbase * 32;                    // wave-uniform LDS offset
            stage16(gx_h + go, sXH + lo);
            stage16(gx_l + go, sXL + lo);
            stage16(gw   + go, sWB + lo);
        }
        __syncthreads();

        short8 af[4], bf[4];
        #pragma unroll
        for (int f = 0; f < 4; ++f) {
            bf[f] = *(const short8*)&sWB[boff + f * 16 * 32];
            af[f] = *(const short8*)&sXH[aoff + f * 16 * 32];
        }
        if (which < 2) {
            #pragma unroll
            for (int fm = 0; fm < 4; ++fm)
                #pragma unroll
                for (int fn = 0; fn < 4; ++fn)
                    acc[fm][fn] = __builtin_amdgcn_mfma_f32_16x16x32_bf16(
                        bf[fn], af[fm], acc[fm][fn], 0, 0, 0);   // C^T
        } else {
            #pragma unroll
            for (int fm = 0; fm < 4; ++fm)
                #pragma unroll
                for (int fn = 0; fn < 4; ++fn)
                    acc[fm][fn] = __builtin_amdgcn_mfma_f32_16x16x32_bf16(
                        af[fm], bf[fn], acc[fm][fn], 0, 0, 0);
        }
        #pragma unroll
        for (int f = 0; f < 4; ++f)
            af[f] = *(const short8*)&sXL[aoff + f * 16 * 32];
        if (which < 2) {
            #pragma unroll
            for (int fm = 0; fm < 4; ++fm)
                #pragma unroll
                for (int fn = 0; fn < 4; ++fn)
                    acc[fm][fn] = __builtin_amdgcn_mfma_f32_16x16x32_bf16(
                        bf[fn], af[fm], acc[fm][fn], 0, 0, 0);   // C^T
        } else {
            #pragma unroll
            for (int fm = 0; fm < 4; ++fm)
                #pragma unroll
                for (int fn = 0; fn < 4; ++fn)
                    acc[fm][fn] = __builtin_amdgcn_mfma_f32_16x16x32_bf16(
                        af[fm], bf[fn], acc[fm][fn], 0, 0, 0);
        }
    }

    const float RLOG = 9.210340371976184f / 32.0f;   // ln(10000)/32
    if (which < 2) {
        unsigned short* dst = (which == 0) ? qst : kst;
        const float scale = (which == 0) ? 0.125f : 1.0f;   // D^-0.5 folded into q
        #pragma unroll
        for (int fm = 0; fm < 4; ++fm) {
            const int s_g = m0 + wm + fm * 16 + col;     // C^T col = x row = s
            const int b = s_g >> 11, s = s_g & 2047;
            const float sf = (float)s;
            #pragma unroll
            for (int fn = 0; fn < 4; ++fn) {
                const int nl = (n0 & 1023) + wn + fn * 16 + quad * 4;  // C^T row = w col
                const int h = nl >> 6;
                const int d0 = nl & 63;                  // multiple of 4
                floatx4 c = acc[fm][fn];
                float o_[4];
                #pragma unroll
                for (int pp = 0; pp < 2; ++pp) {
                    int de = d0 + pp * 2;                // even
                    float fe = __expf(-(float)(de & 31) * RLOG);
                    float fo = __expf(-(float)((de + 1) & 31) * RLOG);
                    float se, ce, so, co;
                    sincosf(sf * fe, &se, &ce);
                    sincosf(sf * fo, &so, &co);
                    float qe = c[pp * 2], qo = c[pp * 2 + 1];
                    o_[pp * 2]     = (qe * ce - qo * se) * scale;
                    o_[pp * 2 + 1] = (qo * co + qe * so) * scale;
                }
                ushort4 o4;
                o4.x = f2bf(o_[0]); o4.y = f2bf(o_[1]);
                o4.z = f2bf(o_[2]); o4.w = f2bf(o_[3]);
                *(ushort4*)(dst + ((size_t)(b * 16 + h) * 2048 + s) * 64 + d0) = o4;
            }
        }
    } else {
        #pragma unroll
        for (int fm = 0; fm < 4; ++fm) {
            const int m = m0 + wm + fm * 16 + quad * 4;  // 4 consecutive s (regs)
            const int b = m >> 11, s0 = m & 2047;
            #pragma unroll
            for (int fn = 0; fn < 4; ++fn) {
                const int nl = (n0 & 1023) + wn + fn * 16 + col;
                const int h = nl >> 6;
                const int d = nl & 63;
                floatx4 c = acc[fm][fn];
                ushort4 o4;
                o4.x = f2bf(c[0]); o4.y = f2bf(c[1]);
                o4.z = f2bf(c[2]); o4.w = f2bf(c[3]);
                *(ushort4*)(vtT + ((size_t)(b * 16 + h) * 64 + d) * 2048 + s0) = o4;
            }
        }
    }
}

// ---------------------------------------------------------------------------
// Attention: complement-masked, bf16 MFMA, single pass (R8-verified).
// ---------------------------------------------------------------------------
__global__ __launch_bounds__(256) void attn_mfma(
    const unsigned short* __restrict__ qst,
    const unsigned short* __restrict__ kst,
    const unsigned short* __restrict__ vtT,
    unsigned short* __restrict__ attn)
{
    __shared__ unsigned short p_tile[4][16][32];

    const int tid  = threadIdx.x;
    const int wave = tid >> 6;
    const int lane = tid & 63;
    const int col  = lane & 15;
    const int quad = lane >> 4;

    const int bh   = blockIdx.x >> 5;
    const int row0 = (blockIdx.x & 31) * 64 + wave * 16;

    const size_t base = (size_t)bh * SEQ * HDIM;

    const unsigned short* qp = qst + base + (size_t)(row0 + col) * HDIM + quad * 8;
    short8 aq0 = *(const short8*)(qp);
    short8 aq1 = *(const short8*)(qp + 32);

    int iR[4], ngR[4], j0R[4];
    #pragma unroll
    for (int r = 0; r < 4; ++r) {
        int i = row0 + quad * 4 + r;
        iR[r] = i;
        ngR[r] = (i + 1 < 4) ? (i + 1) : 4;
        int L = i - 128;
        int bs = (i >> 8) << 8;
        if (bs < L) L = bs;
        if (L < 0) L = 0;
        j0R[r] = (L > 4) ? L : 4;
    }

    floatx4 o0 = {0.f, 0.f, 0.f, 0.f}, o1 = o0, o2 = o0, o3 = o0;
    float lsum[4] = {0.f, 0.f, 0.f, 0.f};

    for (int c32 = 0; c32 < SEQ / 32; ++c32) {
        const int kc0 = c32 * 32;
        #pragma unroll
        for (int h16 = 0; h16 < 2; ++h16) {
            const int kc = kc0 + h16 * 16;
            const unsigned short* kp = kst + base + (size_t)(kc + col) * HDIM + quad * 8;
            short8 bk0 = *(const short8*)(kp);
            short8 bk1 = *(const short8*)(kp + 32);
            floatx4 s = {0.f, 0.f, 0.f, 0.f};
            s = __builtin_amdgcn_mfma_f32_16x16x32_bf16(aq0, bk0, s, 0, 0, 0);
            s = __builtin_amdgcn_mfma_f32_16x16x32_bf16(aq1, bk1, s, 0, 0, 0);
            const int j = kc + col;
            #pragma unroll
            for (int r = 0; r < 4; ++r) {
                bool excl = (j < ngR[r]) || (j >= j0R[r] && j <= iR[r]);
                float p = excl ? 0.f : __expf(s[r]);
                unsigned short pb = f2bf(p);
                lsum[r] += bf2f(pb);
                p_tile[wave][quad * 4 + r][h16 * 16 + col] = pb;
            }
        }
        __syncthreads();
        short8 ap = *(const short8*)&p_tile[wave][col][quad * 8];
        const unsigned short* vp = vtT + base + (size_t)col * SEQ + kc0 + quad * 8;
        short8 bv0 = *(const short8*)(vp);
        short8 bv1 = *(const short8*)(vp + 16 * SEQ);
        short8 bv2 = *(const short8*)(vp + 32 * SEQ);
        short8 bv3 = *(const short8*)(vp + 48 * SEQ);
        o0 = __builtin_amdgcn_mfma_f32_16x16x32_bf16(ap, bv0, o0, 0, 0, 0);
        o1 = __builtin_amdgcn_mfma_f32_16x16x32_bf16(ap, bv1, o1, 0, 0, 0);
        o2 = __builtin_amdgcn_mfma_f32_16x16x32_bf16(ap, bv2, o2, 0, 0, 0);
        o3 = __builtin_amdgcn_mfma_f32_16x16x32_bf16(ap, bv3, o3, 0, 0, 0);
    }

    #pragma unroll
    for (int r = 0; r < 4; ++r) {
        float v = lsum[r];
        v += __shfl_xor(v, 1);
        v += __shfl_xor(v, 2);
        v += __shfl_xor(v, 4);
        v += __shfl_xor(v, 8);
        lsum[r] = v;
    }

    const int b = bh >> 4, h = bh & 15;
    #pragma unroll
    for (int r = 0; r < 4; ++r) {
        float inv = 1.0f / lsum[r];
        unsigned short* orow = attn + ((size_t)(b * SEQ + iR[r])) * EMBD + h * HDIM + col;
        orow[0]  = f2bf(o0[r] * inv);
        orow[16] = f2bf(o1[r] * inv);
        orow[32] = f2bf(o2[r] * inv);
        orow[48] = f2bf(o3[r] * inv);
    }
}

// ---------------------------------------------------------------------------
// Output projection: out = attn(bf16) @ w_out via 1-pass bf16 MFMA -> fp32.
// ---------------------------------------------------------------------------
__global__ __launch_bounds__(256) void gemm_out_mfma(
    const unsigned short* __restrict__ A,      // [4096][1024] bf16
    const unsigned short* __restrict__ woT,    // [1024 n][1024 k] bf16
    float* __restrict__ out)
{
    __shared__ unsigned short smem[8192];      // 16 KB: 2 tiles [128][32]
    unsigned short* sA = smem;
    unsigned short* sB = smem + 4096;

    const int t = threadIdx.x, wave = t >> 6, lane = t & 63;
    const int col = lane & 15, quad = lane >> 4;
    const int n0 = blockIdx.x * 128;
    const int m0 = blockIdx.y * 128;
    const int wm = (wave >> 1) * 64, wn = (wave & 1) * 64;
    const int srow = lane >> 2;
    const int scol = (lane & 3) * 8;

    floatx4 acc[4][4];
    #pragma unroll
    for (int i = 0; i < 4; ++i)
        #pragma unroll
        for (int j = 0; j < 4; ++j) acc[i][j] = (floatx4){0.f, 0.f, 0.f, 0.f};

    const unsigned short* gA = A   + (size_t)m0 * 1024;
    const unsigned short* gB = woT + (size_t)n0 * 1024;

    const int aoff = (wm + col) * 32 + quad * 8;
    const int boff = (wn + col) * 32 + quad * 8;

    for (int k0 = 0; k0 < 1024; k0 += 32) {
        __syncthreads();
        #pragma unroll
        for (int hh = 0; hh < 2; ++hh) {
            const int rbase = hh * 64 + wave * 16;
            const size_t go = (size_t)(rbase + srow) * 1024 + k0 + scol;
            const int lo = rbase * 32;
            stage16(gA + go, sA + lo);
            stage16(gB + go, sB + lo);
        }
        __syncthreads();

        short8 af[4];
        #pragma unroll
        for (int f = 0; f < 4; ++f)
            af[f] = *(const short8*)&sA[aoff + f * 16 * 32];
        #pragma unroll
        for (int fn = 0; fn < 4; ++fn) {
            short8 bf1 = *(const short8*)&sB[boff + fn * 16 * 32];
            #pragma unroll
            for (int fm = 0; fm < 4; ++fm)
                acc[fm][fn] = __builtin_amdgcn_mfma_f32_16x16x32_bf16(
                    af[fm], bf1, acc[fm][fn], 0, 0, 0);
        }
    }

    #pragma unroll
    for (int fm = 0; fm < 4; ++fm) {
        const int m = m0 + wm + fm * 16 + quad * 4;
        #pragma unroll
        for (int fn = 0; fn < 4; ++fn) {
            const int n = n0 + wn + fn * 16 + col;
            floatx4 c = acc[fm][fn];
            out[(size_t)(m + 0) * 1024 + n] = c[0];
            out[(size_t)(m + 1) * 1024 + n] = c[1];
            out[(size_t)(m + 2) * 1024 + n] = c[2];
            out[(size_t)(m + 3) * 1024 + n] = c[3];
        }
    }
}

// ---------------------------------------------------------------------------
extern "C" void kernel_launch(void* const* d_in, const int* in_sizes, int n_in,
                              void* d_out, int out_size, void* d_ws, size_t ws_size,
                              hipStream_t stream) {
    const float* x     = (const float*)d_in[0];  // (2,2048,1024)
    const float* w_qkv = (const float*)d_in[1];  // (1024,3072)
    const float* w_out = (const float*)d_in[2];  // (1024,1024)
    float* out = (float*)d_out;                  // (2,2048,1024)

    // Workspace map (bf16 elems; ~59 MB of the proven >=64 MB):
    unsigned short* ws16 = (unsigned short*)d_ws;
    unsigned short* xh  = ws16;              // 4,194,304
    unsigned short* xl  = ws16 +  4194304;   // 4,194,304
    unsigned short* wbT = ws16 +  8388608;   // 3,145,728  [3072][1024]
    unsigned short* woT = ws16 + 11534336;   // 1,048,576  [1024][1024]
    unsigned short* qst = ws16 + 12582912;   // 4,194,304  [bh][s][d]
    unsigned short* kst = ws16 + 16777216;   // 4,194,304  [bh][s][d]
    unsigned short* vtT = ws16 + 20971520;   // 4,194,304  [bh][d][s]
    unsigned short* aws = ws16 + 25165824;   // 4,194,304  [M][E] bf16

    dim3 blk(256);
    cast_x<<<dim3(4096), blk, 0, stream>>>(x, xh, xl);
    cast_wT<<<dim3(48, 16), blk, 0, stream>>>(w_qkv, wbT, NQKV);
    cast_wT<<<dim3(16, 16), blk, 0, stream>>>(w_out, woT, EMBD);

    gemm_qkv_mfma<<<dim3(NQKV / 128, MROWS / 128), blk, 0, stream>>>(
        xh, xl, wbT, qst, kst, vtT);

    attn_mfma<<<dim3(32 * 32), blk, 0, stream>>>(qst, kst, vtT, aws);

    gemm_out_mfma<<<dim3(EMBD / 128, MROWS / 128), blk, 0, stream>>>(aws, woT, out);
}

// Round 12
// 504.845 us; speedup vs baseline: 1.3526x; 1.1674x over previous
//
#include <hip/hip_runtime.h>
#include <hip/hip_bf16.h>

// Problem constants
#define EMBD   1024
#define NHEAD  16
#define HDIM   64
#define SEQ    2048
#define BATCH  2
#define MROWS  4096          // BATCH*SEQ
#define NQKV   3072          // 3*EMBD

using floatx4 = __attribute__((ext_vector_type(4))) float;
using short8  = __attribute__((ext_vector_type(8))) short;

static __device__ __forceinline__ float bf2f(unsigned short u) {
    unsigned int v = ((unsigned int)u) << 16;
    return __uint_as_float(v);
}
static __device__ __forceinline__ unsigned short f2bf(float f) {
    __hip_bfloat16 h = __float2bfloat16(f);   // RNE
    return *reinterpret_cast<unsigned short*>(&h);
}

// ---------------------------------------------------------------------------
// Cast kernels: x -> split bf16 (hi + lo); w -> bf16, transposed to [N][K].
// ---------------------------------------------------------------------------
__global__ __launch_bounds__(256) void cast_x(
    const float* __restrict__ x, unsigned short* __restrict__ xh,
    unsigned short* __restrict__ xl)
{
    int idx = (blockIdx.x * 256 + threadIdx.x) * 4;
    float4 v = *(const float4*)(x + idx);
    ushort4 h, l;
    h.x = f2bf(v.x); l.x = f2bf(v.x - bf2f(h.x));
    h.y = f2bf(v.y); l.y = f2bf(v.y - bf2f(h.y));
    h.z = f2bf(v.z); l.z = f2bf(v.z - bf2f(h.z));
    h.w = f2bf(v.w); l.w = f2bf(v.w - bf2f(h.w));
    *(ushort4*)(xh + idx) = h;
    *(ushort4*)(xl + idx) = l;
}

// w [1024][N] fp32 -> wT [N][1024] bf16 (64x64 LDS-tiled transpose)
__global__ __launch_bounds__(256) void cast_wT(
    const float* __restrict__ w, unsigned short* __restrict__ wT, int N)
{
    __shared__ unsigned short th[64][65];
    const int k0 = blockIdx.y * 64, n0 = blockIdx.x * 64;
    const int t = threadIdx.x;
    const int r = t >> 4, c = (t & 15) * 4;
    for (int rr = r; rr < 64; rr += 16) {
        float4 v = *(const float4*)(w + (size_t)(k0 + rr) * N + n0 + c);
        th[rr][c + 0] = f2bf(v.x);
        th[rr][c + 1] = f2bf(v.y);
        th[rr][c + 2] = f2bf(v.z);
        th[rr][c + 3] = f2bf(v.w);
    }
    __syncthreads();
    for (int rr = r; rr < 64; rr += 16) {
        ushort4 h;
        h.x = th[c + 0][rr]; h.y = th[c + 1][rr];
        h.z = th[c + 2][rr]; h.w = th[c + 3][rr];
        *(ushort4*)(wT + (size_t)(n0 + rr) * 1024 + k0 + c) = h;
    }
}

// ---------------------------------------------------------------------------
// qkv = x @ w_qkv via split-x bf16 MFMA (xh.wb + xl.wb), fused RoPE.
// LDS-FREE: each wave owns an independent 64x64 output tile; A/B fragments
// load directly global->VGPR (lane addr = row(col)*1024 + quad*8 -> 16 cols
// x 4 quads = 64B-granule coalesced).  No barriers -> compiler pipelines the
// K-loop with plain vmcnt.  (R9-R11: global_load_lds staging produced 1.3-1.5
// GB TCC writes and capped MfmaUtil at 6-11%.)
// q/k: operand-swapped MFMA (acc = C^T) -> lane regs = 4 consecutive d at
// fixed s -> in-lane RoPE pairs, 8B stores into [bh][s][d].
// v: normal orientation -> 4 consecutive s at fixed d -> 8B stores into
// transposed [bh][d][s].
// ---------------------------------------------------------------------------
__global__ __launch_bounds__(256) void gemm_qkv_mfma(
    const unsigned short* __restrict__ xh, const unsigned short* __restrict__ xl,
    const unsigned short* __restrict__ wbT,
    unsigned short* __restrict__ qst, unsigned short* __restrict__ kst,
    unsigned short* __restrict__ vtT)
{
    const int t = threadIdx.x, wave = t >> 6, lane = t & 63;
    const int col = lane & 15, quad = lane >> 4;
    const int n0 = blockIdx.x * 128;
    const int m0 = blockIdx.y * 128;
    const int which = n0 >> 10;              // block-uniform: 0=q,1=k,2=v
    const int wm = (wave >> 1) * 64, wn = (wave & 1) * 64;

    floatx4 acc[4][4];
    #pragma unroll
    for (int i = 0; i < 4; ++i)
        #pragma unroll
        for (int j = 0; j < 4; ++j) acc[i][j] = (floatx4){0.f, 0.f, 0.f, 0.f};

    // per-lane fragment base pointers (16 B loads, 64B-granule coalesced)
    const unsigned short* pa_h = xh  + (size_t)(m0 + wm + col) * 1024 + quad * 8;
    const unsigned short* pa_l = xl  + (size_t)(m0 + wm + col) * 1024 + quad * 8;
    const unsigned short* pb   = wbT + (size_t)(n0 + wn + col) * 1024 + quad * 8;

    for (int k0 = 0; k0 < 1024; k0 += 32) {
        short8 bf[4], ah[4], al[4];
        #pragma unroll
        for (int f = 0; f < 4; ++f) bf[f] = *(const short8*)(pb   + f * 16 * 1024 + k0);
        #pragma unroll
        for (int f = 0; f < 4; ++f) ah[f] = *(const short8*)(pa_h + f * 16 * 1024 + k0);
        #pragma unroll
        for (int f = 0; f < 4; ++f) al[f] = *(const short8*)(pa_l + f * 16 * 1024 + k0);

        if (which < 2) {
            #pragma unroll
            for (int fm = 0; fm < 4; ++fm)
                #pragma unroll
                for (int fn = 0; fn < 4; ++fn) {
                    acc[fm][fn] = __builtin_amdgcn_mfma_f32_16x16x32_bf16(
                        bf[fn], ah[fm], acc[fm][fn], 0, 0, 0);   // C^T
                    acc[fm][fn] = __builtin_amdgcn_mfma_f32_16x16x32_bf16(
                        bf[fn], al[fm], acc[fm][fn], 0, 0, 0);
                }
        } else {
            #pragma unroll
            for (int fm = 0; fm < 4; ++fm)
                #pragma unroll
                for (int fn = 0; fn < 4; ++fn) {
                    acc[fm][fn] = __builtin_amdgcn_mfma_f32_16x16x32_bf16(
                        ah[fm], bf[fn], acc[fm][fn], 0, 0, 0);
                    acc[fm][fn] = __builtin_amdgcn_mfma_f32_16x16x32_bf16(
                        al[fm], bf[fn], acc[fm][fn], 0, 0, 0);
                }
        }
    }

    const float RLOG = 9.210340371976184f / 32.0f;   // ln(10000)/32
    if (which < 2) {
        unsigned short* dst = (which == 0) ? qst : kst;
        const float scale = (which == 0) ? 0.125f : 1.0f;   // D^-0.5 folded into q
        #pragma unroll
        for (int fm = 0; fm < 4; ++fm) {
            const int s_g = m0 + wm + fm * 16 + col;     // C^T col = x row = s
            const int b = s_g >> 11, s = s_g & 2047;
            const float sf = (float)s;
            #pragma unroll
            for (int fn = 0; fn < 4; ++fn) {
                const int nl = (n0 & 1023) + wn + fn * 16 + quad * 4;  // C^T row = w col
                const int h = nl >> 6;
                const int d0 = nl & 63;                  // multiple of 4
                floatx4 c = acc[fm][fn];
                float o_[4];
                #pragma unroll
                for (int pp = 0; pp < 2; ++pp) {
                    int de = d0 + pp * 2;                // even
                    float fe = __expf(-(float)(de & 31) * RLOG);
                    float fo = __expf(-(float)((de + 1) & 31) * RLOG);
                    float se, ce, so, co;
                    sincosf(sf * fe, &se, &ce);
                    sincosf(sf * fo, &so, &co);
                    float qe = c[pp * 2], qo = c[pp * 2 + 1];
                    o_[pp * 2]     = (qe * ce - qo * se) * scale;
                    o_[pp * 2 + 1] = (qo * co + qe * so) * scale;
                }
                ushort4 o4;
                o4.x = f2bf(o_[0]); o4.y = f2bf(o_[1]);
                o4.z = f2bf(o_[2]); o4.w = f2bf(o_[3]);
                *(ushort4*)(dst + ((size_t)(b * 16 + h) * 2048 + s) * 64 + d0) = o4;
            }
        }
    } else {
        #pragma unroll
        for (int fm = 0; fm < 4; ++fm) {
            const int m = m0 + wm + fm * 16 + quad * 4;  // 4 consecutive s (regs)
            const int b = m >> 11, s0 = m & 2047;
            #pragma unroll
            for (int fn = 0; fn < 4; ++fn) {
                const int nl = (n0 & 1023) + wn + fn * 16 + col;
                const int h = nl >> 6;
                const int d = nl & 63;
                floatx4 c = acc[fm][fn];
                ushort4 o4;
                o4.x = f2bf(c[0]); o4.y = f2bf(c[1]);
                o4.z = f2bf(c[2]); o4.w = f2bf(c[3]);
                *(ushort4*)(vtT + ((size_t)(b * 16 + h) * 64 + d) * 2048 + s0) = o4;
            }
        }
    }
}

// ---------------------------------------------------------------------------
// Attention: complement-masked, bf16 MFMA, single pass (R8-verified).
// p_tile slice is wave-private -> NO __syncthreads needed (intra-wave LDS
// ordering is enforced by compiler-inserted lgkmcnt waits).
// ---------------------------------------------------------------------------
__global__ __launch_bounds__(256) void attn_mfma(
    const unsigned short* __restrict__ qst,
    const unsigned short* __restrict__ kst,
    const unsigned short* __restrict__ vtT,
    unsigned short* __restrict__ attn)
{
    __shared__ unsigned short p_tile[4][16][32];

    const int tid  = threadIdx.x;
    const int wave = tid >> 6;
    const int lane = tid & 63;
    const int col  = lane & 15;
    const int quad = lane >> 4;

    const int bh   = blockIdx.x >> 5;
    const int row0 = (blockIdx.x & 31) * 64 + wave * 16;

    const size_t base = (size_t)bh * SEQ * HDIM;

    const unsigned short* qp = qst + base + (size_t)(row0 + col) * HDIM + quad * 8;
    short8 aq0 = *(const short8*)(qp);
    short8 aq1 = *(const short8*)(qp + 32);

    int iR[4], ngR[4], j0R[4];
    #pragma unroll
    for (int r = 0; r < 4; ++r) {
        int i = row0 + quad * 4 + r;
        iR[r] = i;
        ngR[r] = (i + 1 < 4) ? (i + 1) : 4;
        int L = i - 128;
        int bs = (i >> 8) << 8;
        if (bs < L) L = bs;
        if (L < 0) L = 0;
        j0R[r] = (L > 4) ? L : 4;
    }

    floatx4 o0 = {0.f, 0.f, 0.f, 0.f}, o1 = o0, o2 = o0, o3 = o0;
    float lsum[4] = {0.f, 0.f, 0.f, 0.f};

    for (int c32 = 0; c32 < SEQ / 32; ++c32) {
        const int kc0 = c32 * 32;
        #pragma unroll
        for (int h16 = 0; h16 < 2; ++h16) {
            const int kc = kc0 + h16 * 16;
            const unsigned short* kp = kst + base + (size_t)(kc + col) * HDIM + quad * 8;
            short8 bk0 = *(const short8*)(kp);
            short8 bk1 = *(const short8*)(kp + 32);
            floatx4 s = {0.f, 0.f, 0.f, 0.f};
            s = __builtin_amdgcn_mfma_f32_16x16x32_bf16(aq0, bk0, s, 0, 0, 0);
            s = __builtin_amdgcn_mfma_f32_16x16x32_bf16(aq1, bk1, s, 0, 0, 0);
            const int j = kc + col;
            #pragma unroll
            for (int r = 0; r < 4; ++r) {
                bool excl = (j < ngR[r]) || (j >= j0R[r] && j <= iR[r]);
                float p = excl ? 0.f : __expf(s[r]);
                unsigned short pb = f2bf(p);
                lsum[r] += bf2f(pb);
                p_tile[wave][quad * 4 + r][h16 * 16 + col] = pb;
            }
        }
        // wave-private LDS slice: no barrier, compiler orders via lgkmcnt
        short8 ap = *(const short8*)&p_tile[wave][col][quad * 8];
        const unsigned short* vp = vtT + base + (size_t)col * SEQ + kc0 + quad * 8;
        short8 bv0 = *(const short8*)(vp);
        short8 bv1 = *(const short8*)(vp + 16 * SEQ);
        short8 bv2 = *(const short8*)(vp + 32 * SEQ);
        short8 bv3 = *(const short8*)(vp + 48 * SEQ);
        o0 = __builtin_amdgcn_mfma_f32_16x16x32_bf16(ap, bv0, o0, 0, 0, 0);
        o1 = __builtin_amdgcn_mfma_f32_16x16x32_bf16(ap, bv1, o1, 0, 0, 0);
        o2 = __builtin_amdgcn_mfma_f32_16x16x32_bf16(ap, bv2, o2, 0, 0, 0);
        o3 = __builtin_amdgcn_mfma_f32_16x16x32_bf16(ap, bv3, o3, 0, 0, 0);
    }

    #pragma unroll
    for (int r = 0; r < 4; ++r) {
        float v = lsum[r];
        v += __shfl_xor(v, 1);
        v += __shfl_xor(v, 2);
        v += __shfl_xor(v, 4);
        v += __shfl_xor(v, 8);
        lsum[r] = v;
    }

    const int b = bh >> 4, h = bh & 15;
    #pragma unroll
    for (int r = 0; r < 4; ++r) {
        float inv = 1.0f / lsum[r];
        unsigned short* orow = attn + ((size_t)(b * SEQ + iR[r])) * EMBD + h * HDIM + col;
        orow[0]  = f2bf(o0[r] * inv);
        orow[16] = f2bf(o1[r] * inv);
        orow[32] = f2bf(o2[r] * inv);
        orow[48] = f2bf(o3[r] * inv);
    }
}

// ---------------------------------------------------------------------------
// Output projection: out = attn(bf16) @ w_out, LDS-free MFMA -> fp32.
// ---------------------------------------------------------------------------
__global__ __launch_bounds__(256) void gemm_out_mfma(
    const unsigned short* __restrict__ A,      // [4096][1024] bf16
    const unsigned short* __restrict__ woT,    // [1024 n][1024 k] bf16
    float* __restrict__ out)
{
    const int t = threadIdx.x, wave = t >> 6, lane = t & 63;
    const int col = lane & 15, quad = lane >> 4;
    const int n0 = blockIdx.x * 128;
    const int m0 = blockIdx.y * 128;
    const int wm = (wave >> 1) * 64, wn = (wave & 1) * 64;

    floatx4 acc[4][4];
    #pragma unroll
    for (int i = 0; i < 4; ++i)
        #pragma unroll
        for (int j = 0; j < 4; ++j) acc[i][j] = (floatx4){0.f, 0.f, 0.f, 0.f};

    const unsigned short* pa = A   + (size_t)(m0 + wm + col) * 1024 + quad * 8;
    const unsigned short* pb = woT + (size_t)(n0 + wn + col) * 1024 + quad * 8;

    for (int k0 = 0; k0 < 1024; k0 += 32) {
        short8 af[4], bf[4];
        #pragma unroll
        for (int f = 0; f < 4; ++f) bf[f] = *(const short8*)(pb + f * 16 * 1024 + k0);
        #pragma unroll
        for (int f = 0; f < 4; ++f) af[f] = *(const short8*)(pa + f * 16 * 1024 + k0);
        #pragma unroll
        for (int fm = 0; fm < 4; ++fm)
            #pragma unroll
            for (int fn = 0; fn < 4; ++fn)
                acc[fm][fn] = __builtin_amdgcn_mfma_f32_16x16x32_bf16(
                    af[fm], bf[fn], acc[fm][fn], 0, 0, 0);
    }

    #pragma unroll
    for (int fm = 0; fm < 4; ++fm) {
        const int m = m0 + wm + fm * 16 + quad * 4;
        #pragma unroll
        for (int fn = 0; fn < 4; ++fn) {
            const int n = n0 + wn + fn * 16 + col;
            floatx4 c = acc[fm][fn];
            out[(size_t)(m + 0) * 1024 + n] = c[0];
            out[(size_t)(m + 1) * 1024 + n] = c[1];
            out[(size_t)(m + 2) * 1024 + n] = c[2];
            out[(size_t)(m + 3) * 1024 + n] = c[3];
        }
    }
}

// ---------------------------------------------------------------------------
extern "C" void kernel_launch(void* const* d_in, const int* in_sizes, int n_in,
                              void* d_out, int out_size, void* d_ws, size_t ws_size,
                              hipStream_t stream) {
    const float* x     = (const float*)d_in[0];  // (2,2048,1024)
    const float* w_qkv = (const float*)d_in[1];  // (1024,3072)
    const float* w_out = (const float*)d_in[2];  // (1024,1024)
    float* out = (float*)d_out;                  // (2,2048,1024)

    // Workspace map (bf16 elems; ~59 MB of the proven >=64 MB):
    unsigned short* ws16 = (unsigned short*)d_ws;
    unsigned short* xh  = ws16;              // 4,194,304
    unsigned short* xl  = ws16 +  4194304;   // 4,194,304
    unsigned short* wbT = ws16 +  8388608;   // 3,145,728  [3072][1024]
    unsigned short* woT = ws16 + 11534336;   // 1,048,576  [1024][1024]
    unsigned short* qst = ws16 + 12582912;   // 4,194,304  [bh][s][d]
    unsigned short* kst = ws16 + 16777216;   // 4,194,304  [bh][s][d]
    unsigned short* vtT = ws16 + 20971520;   // 4,194,304  [bh][d][s]
    unsigned short* aws = ws16 + 25165824;   // 4,194,304  [M][E] bf16

    dim3 blk(256);
    cast_x<<<dim3(4096), blk, 0, stream>>>(x, xh, xl);
    cast_wT<<<dim3(48, 16), blk, 0, stream>>>(w_qkv, wbT, NQKV);
    cast_wT<<<dim3(16, 16), blk, 0, stream>>>(w_out, woT, EMBD);

    gemm_qkv_mfma<<<dim3(NQKV / 128, MROWS / 128), blk, 0, stream>>>(
        xh, xl, wbT, qst, kst, vtT);

    attn_mfma<<<dim3(32 * 32), blk, 0, stream>>>(qst, kst, vtT, aws);

    gemm_out_mfma<<<dim3(EMBD / 128, MROWS / 128), blk, 0, stream>>>(aws, woT, out);
}

// Round 13
// 443.976 us; speedup vs baseline: 1.5381x; 1.1371x over previous
//
#include <hip/hip_runtime.h>
#include <hip/hip_bf16.h>

// Problem constants
#define EMBD   1024
#define NHEAD  16
#define HDIM   64
#define SEQ    2048
#define BATCH  2
#define MROWS  4096          // BATCH*SEQ
#define NQKV   3072          // 3*EMBD
#define VSTR   2064          // padded vtT row stride (breaks 4KB L2 aliasing)

using floatx4 = __attribute__((ext_vector_type(4))) float;
using short8  = __attribute__((ext_vector_type(8))) short;

static __device__ __forceinline__ float bf2f(unsigned short u) {
    unsigned int v = ((unsigned int)u) << 16;
    return __uint_as_float(v);
}
static __device__ __forceinline__ unsigned short f2bf(float f) {
    __hip_bfloat16 h = __float2bfloat16(f);   // RNE
    return *reinterpret_cast<unsigned short*>(&h);
}

// ---------------------------------------------------------------------------
// Cast kernels: x -> split bf16 (hi + lo); w -> bf16, transposed to [N][K].
// ---------------------------------------------------------------------------
__global__ __launch_bounds__(256) void cast_x(
    const float* __restrict__ x, unsigned short* __restrict__ xh,
    unsigned short* __restrict__ xl)
{
    int idx = (blockIdx.x * 256 + threadIdx.x) * 4;
    float4 v = *(const float4*)(x + idx);
    ushort4 h, l;
    h.x = f2bf(v.x); l.x = f2bf(v.x - bf2f(h.x));
    h.y = f2bf(v.y); l.y = f2bf(v.y - bf2f(h.y));
    h.z = f2bf(v.z); l.z = f2bf(v.z - bf2f(h.z));
    h.w = f2bf(v.w); l.w = f2bf(v.w - bf2f(h.w));
    *(ushort4*)(xh + idx) = h;
    *(ushort4*)(xl + idx) = l;
}

// w [1024][N] fp32 -> wT [N][1024] bf16 (64x64 LDS-tiled transpose)
__global__ __launch_bounds__(256) void cast_wT(
    const float* __restrict__ w, unsigned short* __restrict__ wT, int N)
{
    __shared__ unsigned short th[64][65];
    const int k0 = blockIdx.y * 64, n0 = blockIdx.x * 64;
    const int t = threadIdx.x;
    const int r = t >> 4, c = (t & 15) * 4;
    for (int rr = r; rr < 64; rr += 16) {
        float4 v = *(const float4*)(w + (size_t)(k0 + rr) * N + n0 + c);
        th[rr][c + 0] = f2bf(v.x);
        th[rr][c + 1] = f2bf(v.y);
        th[rr][c + 2] = f2bf(v.z);
        th[rr][c + 3] = f2bf(v.w);
    }
    __syncthreads();
    for (int rr = r; rr < 64; rr += 16) {
        ushort4 h;
        h.x = th[c + 0][rr]; h.y = th[c + 1][rr];
        h.z = th[c + 2][rr]; h.w = th[c + 3][rr];
        *(ushort4*)(wT + (size_t)(n0 + rr) * 1024 + k0 + c) = h;
    }
}

// ---------------------------------------------------------------------------
// qkv = x @ w_qkv via split-x bf16 MFMA (xh.wb + xl.wb), fused RoPE.
// LDS-free (R12-verified).  v epilogue now writes padded vtT (stride VSTR).
// ---------------------------------------------------------------------------
__global__ __launch_bounds__(256) void gemm_qkv_mfma(
    const unsigned short* __restrict__ xh, const unsigned short* __restrict__ xl,
    const unsigned short* __restrict__ wbT,
    unsigned short* __restrict__ qst, unsigned short* __restrict__ kst,
    unsigned short* __restrict__ vtT)
{
    const int t = threadIdx.x, wave = t >> 6, lane = t & 63;
    const int col = lane & 15, quad = lane >> 4;
    const int n0 = blockIdx.x * 128;
    const int m0 = blockIdx.y * 128;
    const int which = n0 >> 10;              // block-uniform: 0=q,1=k,2=v
    const int wm = (wave >> 1) * 64, wn = (wave & 1) * 64;

    floatx4 acc[4][4];
    #pragma unroll
    for (int i = 0; i < 4; ++i)
        #pragma unroll
        for (int j = 0; j < 4; ++j) acc[i][j] = (floatx4){0.f, 0.f, 0.f, 0.f};

    const unsigned short* pa_h = xh  + (size_t)(m0 + wm + col) * 1024 + quad * 8;
    const unsigned short* pa_l = xl  + (size_t)(m0 + wm + col) * 1024 + quad * 8;
    const unsigned short* pb   = wbT + (size_t)(n0 + wn + col) * 1024 + quad * 8;

    for (int k0 = 0; k0 < 1024; k0 += 32) {
        short8 bf[4], ah[4], al[4];
        #pragma unroll
        for (int f = 0; f < 4; ++f) bf[f] = *(const short8*)(pb   + f * 16 * 1024 + k0);
        #pragma unroll
        for (int f = 0; f < 4; ++f) ah[f] = *(const short8*)(pa_h + f * 16 * 1024 + k0);
        #pragma unroll
        for (int f = 0; f < 4; ++f) al[f] = *(const short8*)(pa_l + f * 16 * 1024 + k0);

        if (which < 2) {
            #pragma unroll
            for (int fm = 0; fm < 4; ++fm)
                #pragma unroll
                for (int fn = 0; fn < 4; ++fn) {
                    acc[fm][fn] = __builtin_amdgcn_mfma_f32_16x16x32_bf16(
                        bf[fn], ah[fm], acc[fm][fn], 0, 0, 0);   // C^T
                    acc[fm][fn] = __builtin_amdgcn_mfma_f32_16x16x32_bf16(
                        bf[fn], al[fm], acc[fm][fn], 0, 0, 0);
                }
        } else {
            #pragma unroll
            for (int fm = 0; fm < 4; ++fm)
                #pragma unroll
                for (int fn = 0; fn < 4; ++fn) {
                    acc[fm][fn] = __builtin_amdgcn_mfma_f32_16x16x32_bf16(
                        ah[fm], bf[fn], acc[fm][fn], 0, 0, 0);
                    acc[fm][fn] = __builtin_amdgcn_mfma_f32_16x16x32_bf16(
                        al[fm], bf[fn], acc[fm][fn], 0, 0, 0);
                }
        }
    }

    const float RLOG = 9.210340371976184f / 32.0f;   // ln(10000)/32
    if (which < 2) {
        unsigned short* dst = (which == 0) ? qst : kst;
        const float scale = (which == 0) ? 0.125f : 1.0f;   // D^-0.5 folded into q
        #pragma unroll
        for (int fm = 0; fm < 4; ++fm) {
            const int s_g = m0 + wm + fm * 16 + col;     // C^T col = x row = s
            const int b = s_g >> 11, s = s_g & 2047;
            const float sf = (float)s;
            #pragma unroll
            for (int fn = 0; fn < 4; ++fn) {
                const int nl = (n0 & 1023) + wn + fn * 16 + quad * 4;  // C^T row = w col
                const int h = nl >> 6;
                const int d0 = nl & 63;                  // multiple of 4
                floatx4 c = acc[fm][fn];
                float o_[4];
                #pragma unroll
                for (int pp = 0; pp < 2; ++pp) {
                    int de = d0 + pp * 2;                // even
                    float fe = __expf(-(float)(de & 31) * RLOG);
                    float fo = __expf(-(float)((de + 1) & 31) * RLOG);
                    float se, ce, so, co;
                    sincosf(sf * fe, &se, &ce);
                    sincosf(sf * fo, &so, &co);
                    float qe = c[pp * 2], qo = c[pp * 2 + 1];
                    o_[pp * 2]     = (qe * ce - qo * se) * scale;
                    o_[pp * 2 + 1] = (qo * co + qe * so) * scale;
                }
                ushort4 o4;
                o4.x = f2bf(o_[0]); o4.y = f2bf(o_[1]);
                o4.z = f2bf(o_[2]); o4.w = f2bf(o_[3]);
                *(ushort4*)(dst + ((size_t)(b * 16 + h) * 2048 + s) * 64 + d0) = o4;
            }
        }
    } else {
        #pragma unroll
        for (int fm = 0; fm < 4; ++fm) {
            const int m = m0 + wm + fm * 16 + quad * 4;  // 4 consecutive s (regs)
            const int b = m >> 11, s0 = m & 2047;
            #pragma unroll
            for (int fn = 0; fn < 4; ++fn) {
                const int nl = (n0 & 1023) + wn + fn * 16 + col;
                const int h = nl >> 6;
                const int d = nl & 63;
                floatx4 c = acc[fm][fn];
                ushort4 o4;
                o4.x = f2bf(c[0]); o4.y = f2bf(c[1]);
                o4.z = f2bf(c[2]); o4.w = f2bf(c[3]);
                *(ushort4*)(vtT + (size_t)(b * 16 + h) * 64 * VSTR
                                + (size_t)d * VSTR + s0) = o4;
            }
        }
    }
}

// ---------------------------------------------------------------------------
// Attention: complement-masked, bf16 MFMA, softmax-without-max (additive!).
// KEY-SPLIT: 4 waves share one 16-row q-tile; wave w handles keys
// [w*512, w*512+512).  Partial O and lsum combine exactly (pure sums) via
// LDS; wave 0 stores.  vtT reads use padded stride VSTR.
// Grid: 32 bh x 128 row-tiles = 4096 blocks.
// ---------------------------------------------------------------------------
__global__ __launch_bounds__(256) void attn_mfma(
    const unsigned short* __restrict__ qst,
    const unsigned short* __restrict__ kst,
    const unsigned short* __restrict__ vtT,
    unsigned short* __restrict__ attn)
{
    __shared__ unsigned short p_tile[4][16][32];   // per-wave private
    __shared__ float4 redbuf[3][64][5];            // waves 1..3 partials

    const int tid  = threadIdx.x;
    const int wave = tid >> 6;
    const int lane = tid & 63;
    const int col  = lane & 15;
    const int quad = lane >> 4;

    const int bh   = blockIdx.x >> 7;              // 0..31
    const int row0 = (blockIdx.x & 127) * 16;      // q-tile (shared by 4 waves)

    const size_t base  = (size_t)bh * SEQ * HDIM;
    const size_t vbase = (size_t)bh * HDIM * VSTR;

    const unsigned short* qp = qst + base + (size_t)(row0 + col) * HDIM + quad * 8;
    short8 aq0 = *(const short8*)(qp);
    short8 aq1 = *(const short8*)(qp + 32);

    int iR[4], ngR[4], j0R[4];
    #pragma unroll
    for (int r = 0; r < 4; ++r) {
        int i = row0 + quad * 4 + r;
        iR[r] = i;
        ngR[r] = (i + 1 < 4) ? (i + 1) : 4;
        int L = i - 128;
        int bs = (i >> 8) << 8;
        if (bs < L) L = bs;
        if (L < 0) L = 0;
        j0R[r] = (L > 4) ? L : 4;
    }

    floatx4 o0 = {0.f, 0.f, 0.f, 0.f}, o1 = o0, o2 = o0, o3 = o0;
    float lsum[4] = {0.f, 0.f, 0.f, 0.f};

    const int kbeg = wave * (SEQ / 4);             // 512 keys per wave
    for (int c32 = 0; c32 < (SEQ / 4) / 32; ++c32) {
        const int kc0 = kbeg + c32 * 32;
        #pragma unroll
        for (int h16 = 0; h16 < 2; ++h16) {
            const int kc = kc0 + h16 * 16;
            const unsigned short* kp = kst + base + (size_t)(kc + col) * HDIM + quad * 8;
            short8 bk0 = *(const short8*)(kp);
            short8 bk1 = *(const short8*)(kp + 32);
            floatx4 s = {0.f, 0.f, 0.f, 0.f};
            s = __builtin_amdgcn_mfma_f32_16x16x32_bf16(aq0, bk0, s, 0, 0, 0);
            s = __builtin_amdgcn_mfma_f32_16x16x32_bf16(aq1, bk1, s, 0, 0, 0);
            const int j = kc + col;
            #pragma unroll
            for (int r = 0; r < 4; ++r) {
                bool excl = (j < ngR[r]) || (j >= j0R[r] && j <= iR[r]);
                float p = excl ? 0.f : __expf(s[r]);
                lsum[r] += p;
                p_tile[wave][quad * 4 + r][h16 * 16 + col] = f2bf(p);
            }
        }
        // wave-private LDS slice: no barrier (lgkmcnt-ordered)
        short8 ap = *(const short8*)&p_tile[wave][col][quad * 8];
        const unsigned short* vp = vtT + vbase + (size_t)col * VSTR + kc0 + quad * 8;
        short8 bv0 = *(const short8*)(vp);
        short8 bv1 = *(const short8*)(vp + 16 * VSTR);
        short8 bv2 = *(const short8*)(vp + 32 * VSTR);
        short8 bv3 = *(const short8*)(vp + 48 * VSTR);
        o0 = __builtin_amdgcn_mfma_f32_16x16x32_bf16(ap, bv0, o0, 0, 0, 0);
        o1 = __builtin_amdgcn_mfma_f32_16x16x32_bf16(ap, bv1, o1, 0, 0, 0);
        o2 = __builtin_amdgcn_mfma_f32_16x16x32_bf16(ap, bv2, o2, 0, 0, 0);
        o3 = __builtin_amdgcn_mfma_f32_16x16x32_bf16(ap, bv3, o3, 0, 0, 0);
    }

    // intra-wave lsum reduce over the 16 cols
    #pragma unroll
    for (int r = 0; r < 4; ++r) {
        float v = lsum[r];
        v += __shfl_xor(v, 1);
        v += __shfl_xor(v, 2);
        v += __shfl_xor(v, 4);
        v += __shfl_xor(v, 8);
        lsum[r] = v;
    }

    // cross-wave combine (exact: everything is additive)
    if (wave > 0) {
        redbuf[wave - 1][lane][0] = make_float4(o0[0], o0[1], o0[2], o0[3]);
        redbuf[wave - 1][lane][1] = make_float4(o1[0], o1[1], o1[2], o1[3]);
        redbuf[wave - 1][lane][2] = make_float4(o2[0], o2[1], o2[2], o2[3]);
        redbuf[wave - 1][lane][3] = make_float4(o3[0], o3[1], o3[2], o3[3]);
        redbuf[wave - 1][lane][4] = make_float4(lsum[0], lsum[1], lsum[2], lsum[3]);
    }
    __syncthreads();
    if (wave == 0) {
        #pragma unroll
        for (int w = 0; w < 3; ++w) {
            float4 t0 = redbuf[w][lane][0];
            float4 t1 = redbuf[w][lane][1];
            float4 t2 = redbuf[w][lane][2];
            float4 t3 = redbuf[w][lane][3];
            float4 tl = redbuf[w][lane][4];
            o0[0] += t0.x; o0[1] += t0.y; o0[2] += t0.z; o0[3] += t0.w;
            o1[0] += t1.x; o1[1] += t1.y; o1[2] += t1.z; o1[3] += t1.w;
            o2[0] += t2.x; o2[1] += t2.y; o2[2] += t2.z; o2[3] += t2.w;
            o3[0] += t3.x; o3[1] += t3.y; o3[2] += t3.z; o3[3] += t3.w;
            lsum[0] += tl.x; lsum[1] += tl.y; lsum[2] += tl.z; lsum[3] += tl.w;
        }
        const int b = bh >> 4, h = bh & 15;
        #pragma unroll
        for (int r = 0; r < 4; ++r) {
            float inv = 1.0f / lsum[r];
            unsigned short* orow = attn + ((size_t)(b * SEQ + iR[r])) * EMBD
                                        + h * HDIM + col;
            orow[0]  = f2bf(o0[r] * inv);
            orow[16] = f2bf(o1[r] * inv);
            orow[32] = f2bf(o2[r] * inv);
            orow[48] = f2bf(o3[r] * inv);
        }
    }
}

// ---------------------------------------------------------------------------
// Output projection: out = attn(bf16) @ w_out, LDS-free MFMA -> fp32.
// ---------------------------------------------------------------------------
__global__ __launch_bounds__(256) void gemm_out_mfma(
    const unsigned short* __restrict__ A,      // [4096][1024] bf16
    const unsigned short* __restrict__ woT,    // [1024 n][1024 k] bf16
    float* __restrict__ out)
{
    const int t = threadIdx.x, wave = t >> 6, lane = t & 63;
    const int col = lane & 15, quad = lane >> 4;
    const int n0 = blockIdx.x * 128;
    const int m0 = blockIdx.y * 128;
    const int wm = (wave >> 1) * 64, wn = (wave & 1) * 64;

    floatx4 acc[4][4];
    #pragma unroll
    for (int i = 0; i < 4; ++i)
        #pragma unroll
        for (int j = 0; j < 4; ++j) acc[i][j] = (floatx4){0.f, 0.f, 0.f, 0.f};

    const unsigned short* pa = A   + (size_t)(m0 + wm + col) * 1024 + quad * 8;
    const unsigned short* pb = woT + (size_t)(n0 + wn + col) * 1024 + quad * 8;

    for (int k0 = 0; k0 < 1024; k0 += 32) {
        short8 af[4], bf[4];
        #pragma unroll
        for (int f = 0; f < 4; ++f) bf[f] = *(const short8*)(pb + f * 16 * 1024 + k0);
        #pragma unroll
        for (int f = 0; f < 4; ++f) af[f] = *(const short8*)(pa + f * 16 * 1024 + k0);
        #pragma unroll
        for (int fm = 0; fm < 4; ++fm)
            #pragma unroll
            for (int fn = 0; fn < 4; ++fn)
                acc[fm][fn] = __builtin_amdgcn_mfma_f32_16x16x32_bf16(
                    af[fm], bf[fn], acc[fm][fn], 0, 0, 0);
    }

    #pragma unroll
    for (int fm = 0; fm < 4; ++fm) {
        const int m = m0 + wm + fm * 16 + quad * 4;
        #pragma unroll
        for (int fn = 0; fn < 4; ++fn) {
            const int n = n0 + wn + fn * 16 + col;
            floatx4 c = acc[fm][fn];
            out[(size_t)(m + 0) * 1024 + n] = c[0];
            out[(size_t)(m + 1) * 1024 + n] = c[1];
            out[(size_t)(m + 2) * 1024 + n] = c[2];
            out[(size_t)(m + 3) * 1024 + n] = c[3];
        }
    }
}

// ---------------------------------------------------------------------------
extern "C" void kernel_launch(void* const* d_in, const int* in_sizes, int n_in,
                              void* d_out, int out_size, void* d_ws, size_t ws_size,
                              hipStream_t stream) {
    const float* x     = (const float*)d_in[0];  // (2,2048,1024)
    const float* w_qkv = (const float*)d_in[1];  // (1024,3072)
    const float* w_out = (const float*)d_in[2];  // (1024,1024)
    float* out = (float*)d_out;                  // (2,2048,1024)

    // Workspace map (bf16 elems; ~58.8 MB of the proven >=64 MB):
    unsigned short* ws16 = (unsigned short*)d_ws;
    unsigned short* xh  = ws16;              // 4,194,304
    unsigned short* xl  = ws16 +  4194304;   // 4,194,304
    unsigned short* wbT = ws16 +  8388608;   // 3,145,728  [3072][1024]
    unsigned short* woT = ws16 + 11534336;   // 1,048,576  [1024][1024]
    unsigned short* qst = ws16 + 12582912;   // 4,194,304  [bh][s][d]
    unsigned short* kst = ws16 + 16777216;   // 4,194,304  [bh][s][d]
    unsigned short* vtT = ws16 + 20971520;   // 4,227,072  [bh][d][VSTR] padded
    unsigned short* aws = ws16 + 25198592;   // 4,194,304  [M][E] bf16

    dim3 blk(256);
    cast_x<<<dim3(4096), blk, 0, stream>>>(x, xh, xl);
    cast_wT<<<dim3(48, 16), blk, 0, stream>>>(w_qkv, wbT, NQKV);
    cast_wT<<<dim3(16, 16), blk, 0, stream>>>(w_out, woT, EMBD);

    gemm_qkv_mfma<<<dim3(NQKV / 128, MROWS / 128), blk, 0, stream>>>(
        xh, xl, wbT, qst, kst, vtT);

    attn_mfma<<<dim3(32 * 128), blk, 0, stream>>>(qst, kst, vtT, aws);

    gemm_out_mfma<<<dim3(EMBD / 128, MROWS / 128), blk, 0, stream>>>(aws, woT, out);
}